// Round 3
// baseline (240.303 us; speedup 1.0000x reference)
//
#include <hip/hip_runtime.h>
#include <hip/hip_bf16.h>

// Swin shifted-window attention, fused, bf16 MFMA (16x16x32).
// B=16 H=W=128 C=96 NH=3 d=32 WS=8 SS=4 -> L=64 tokens/window, 4096 blocks.
// R7 = R6 (verified) + VALU-diet, structure untouched:
//   - packed f32->bf16 via __float22bfloat162_rn (clang matches gfx950
//     v_cvt_pk_bf16_f32; m240: scalar-cast route beats hand asm) at ALL
//     conversion sites (stage, Q/K/V epilogues, P pack, O pack)
//   - exp -> exp2: Q weights+bias pre-scaled by 1/ln2 in prep; bias table
//     pre-scaled; mask -100 -> -144.2695  => v_exp_f32 with no mul
//   - bias table packed bf16x2 [h][kpair=32][q=64]: 8 dword loads/head vs 16
// Fragment layouts (verified on gfx950 via R4/R6):
//   A: lane holds A[m=lane&15][k=quad*8+j]
//   B: lane holds B[k=quad*8+j][n=lane&15]
//   C/D: lane holds (row=quad*4+reg, col=lane&15)

typedef __attribute__((ext_vector_type(8))) short short8;
typedef __attribute__((ext_vector_type(4))) float f32x4;

#define XST 104   // xs row stride (bf16): 208B, 2-way banks (free)
#define VST 72    // vt row stride: 144B

// ws layout:
//   shorts [0        .. 27647]  qkv_w bf16, row-major [col][96], cols 0..95 pre-scaled by qs/ln2
//   shorts [27648    .. 36863]  proj_w bf16, row-major [col][96]
//   bytes  73728..74879         qkv_b fp32 (288), cols 0..95 pre-scaled by qs/ln2
//   bytes  74880..75263         proj_b fp32 (96)
//   bytes  75776..100351        bias2 u32 [3][32][64]: bf16x2(rel_bias[h][q][2kp], [2kp+1]) / ln2
#define WS_QKVW 0
#define WS_PROJW 27648
#define WS_QKVB_BYTES 73728
#define WS_PROJB_BYTES 74880
#define WS_BIAST_BYTES 75776
#define WS_TOTAL_BYTES (WS_BIAST_BYTES + 3 * 32 * 64 * 4)

#define INV_LN2 1.4426950408889634f
#define MASK_NEG 144.26950408889634f   // 100/ln2

__device__ __forceinline__ unsigned short f2b(float f) {
    union { float f; unsigned u; } v; v.f = f;
    unsigned r = v.u + 0x7fffu + ((v.u >> 16) & 1u);   // RNE
    return (unsigned short)(r >> 16);
}

// packed f32x2 -> bf16x2 (RNE): lo = a, hi = b
__device__ __forceinline__ unsigned pk2(float a, float b) {
    union { __hip_bfloat162 h; unsigned u; } z;
    z.h = __float22bfloat162_rn(make_float2(a, b));
    return z.u;
}
__device__ __forceinline__ float blo(unsigned u) {
    union { unsigned u; float f; } z; z.u = u << 16; return z.f;
}
__device__ __forceinline__ float bhi(unsigned u) {
    union { unsigned u; float f; } z; z.u = u & 0xffff0000u; return z.f;
}

__global__ void prep_weights(const float* __restrict__ qkv_w,
                             const float* __restrict__ qkv_b,
                             const float* __restrict__ proj_w,
                             const float* __restrict__ proj_b,
                             const float* __restrict__ rel_bias,
                             void* __restrict__ ws, int do_bias)
{
    unsigned short* wsh = (unsigned short*)ws;
    float* fqb = (float*)((char*)ws + WS_QKVB_BYTES);
    float* fpb = (float*)((char*)ws + WS_PROJB_BYTES);
    unsigned* fb2 = (unsigned*)((char*)ws + WS_BIAST_BYTES);
    const float qs = 0.17677669529663687f * INV_LN2;  // 1/sqrt(32)/ln2

    int idx = blockIdx.x * 256 + threadIdx.x;
    if (idx < 27648) {                       // qkv_w
        int col = idx / 96;
        float v = qkv_w[idx];
        if (col < 96) v *= qs;
        wsh[WS_QKVW + idx] = f2b(v);
    } else if (idx < 36864) {                // proj_w
        wsh[WS_PROJW + (idx - 27648)] = f2b(proj_w[idx - 27648]);
    } else if (idx < 37152) {                // qkv_b
        int col = idx - 36864;
        float v = qkv_b[col];
        if (col < 96) v *= qs;
        fqb[col] = v;
    } else if (idx < 37248) {                // proj_b
        fpb[idx - 37152] = proj_b[idx - 37152];
    } else if (do_bias && idx < 43392) {     // bias2[h][kp][q]
        int i2 = idx - 37248;                // [0, 6144)
        int h = i2 >> 11;                    // 2048 per head
        int rem = i2 & 2047;
        int kp = rem >> 6, q = rem & 63;
        float lo = rel_bias[(h * 64 + q) * 64 + 2 * kp]     * INV_LN2;
        float hi = rel_bias[(h * 64 + q) * 64 + 2 * kp + 1] * INV_LN2;
        fb2[i2] = pk2(lo, hi);
    }
}

__global__ __launch_bounds__(256, 4) void swin_mfma(
    const float* __restrict__ x,
    const float* __restrict__ rel_bias,     // [h][q][k] fallback path
    const unsigned* __restrict__ bias2,     // [h][kp][q] bf16x2/ln2 in ws, or nullptr
    const void* __restrict__ ws,
    float* __restrict__ out)
{
    const unsigned short* wqkv  = (const unsigned short*)ws + WS_QKVW;
    const unsigned short* wproj = (const unsigned short*)ws + WS_PROJW;
    const float* wqkvb = (const float*)((const char*)ws + WS_QKVB_BYTES);
    const float* wprjb = (const float*)((const char*)ws + WS_PROJB_BYTES);

    __shared__ __align__(16) unsigned short xs[64 * XST];      // 13.0 KB: x -> Q -> attn-out
    __shared__ __align__(16) unsigned short kb[3 * 64 * 32];   // 12.0 KB: K, chunk-XOR swizzled
    __shared__ __align__(16) unsigned short vt[3 * 32 * VST];  // 13.5 KB: v transposed [d][row]
    // total 39424 B -> 4 blocks/CU

    const int t    = threadIdx.x;
    const int wv   = t >> 6;          // wave id 0..3 = q-strip owner
    const int lane = t & 63;
    const int quad = lane >> 4;
    const int l16  = lane & 15;
    const int m0   = wv * 16;

    const int blk = blockIdx.x;
    const int bb  = blk >> 8;
    const int win = blk & 255;
    const int wh  = win >> 4, ww = win & 15;

    // ---- stage x window -> bf16 LDS (rolled coords) ----
    for (int idx = t; idx < 1536; idx += 256) {
        int row = idx / 24;
        int c4  = idx - row * 24;
        int r = row >> 3, c = row & 7;
        int gh = (wh * 8 + r + 4) & 127;
        int gw = (ww * 8 + c + 4) & 127;
        float4 v = *(const float4*)&x[(((bb * 128 + gh) * 128 + gw) * 96) + c4 * 4];
        union { unsigned u[2]; ushort4 s; } pk;
        pk.u[0] = pk2(v.x, v.y);
        pk.u[1] = pk2(v.z, v.w);
        *(ushort4*)&xs[row * XST + c4 * 4] = pk.s;
    }
    __syncthreads();

    // ---- preload X A-frags; then xs is dead and can hold Q ----
    short8 af[4][3];
    #pragma unroll
    for (int mt = 0; mt < 4; ++mt)
        #pragma unroll
        for (int ks = 0; ks < 3; ++ks)
            af[mt][ks] = *(const short8*)&xs[(mt * 16 + l16) * XST + ks * 32 + quad * 8];
    __syncthreads();   // all waves done reading x from xs

    // ---- QKV GEMM: 64x288 = (4 m-tiles) x (18 n-tiles) x (3 k-steps) ----
    for (int nt = wv; nt < 18; nt += 4) {
        const int n0 = nt * 16;
        float bias = wqkvb[n0 + l16];
        f32x4 acc[4];
        #pragma unroll
        for (int mt = 0; mt < 4; ++mt) acc[mt] = (f32x4){bias, bias, bias, bias};
        #pragma unroll
        for (int ks = 0; ks < 3; ++ks) {
            short8 bf = *(const short8*)&wqkv[(n0 + l16) * 96 + ks * 32 + quad * 8];
            #pragma unroll
            for (int mt = 0; mt < 4; ++mt)
                acc[mt] = __builtin_amdgcn_mfma_f32_16x16x32_bf16(af[mt][ks], bf, acc[mt], 0, 0, 0);
        }
        if (nt < 6) {            // Q (pre-scaled by qs/ln2) -> xs[row][col]
            int col = n0 + l16;
            #pragma unroll
            for (int mt = 0; mt < 4; ++mt) {
                unsigned u01 = pk2(acc[mt][0], acc[mt][1]);
                unsigned u23 = pk2(acc[mt][2], acc[mt][3]);
                int rb = (mt * 16 + quad * 4) * XST + col;
                xs[rb]           = (unsigned short)u01;
                xs[rb + XST]     = (unsigned short)(u01 >> 16);
                xs[rb + 2 * XST] = (unsigned short)u23;
                xs[rb + 3 * XST] = (unsigned short)(u23 >> 16);
            }
        } else if (nt < 12) {    // K row-major, stride 32, 16B-chunk XOR swizzle
            int col = n0 - 96 + l16; int hh = col >> 5; int d = col & 31;
            int dch = d >> 3, dlo = d & 7;
            #pragma unroll
            for (int mt = 0; mt < 4; ++mt) {
                int base = hh * 64 + mt * 16 + quad * 4;      // even
                unsigned u01 = pk2(acc[mt][0], acc[mt][1]);
                unsigned u23 = pk2(acc[mt][2], acc[mt][3]);
                int c01 = ((dch ^ ((base >> 1) & 3)) << 3) + dlo;
                int c23 = ((dch ^ (((base >> 1) + 1) & 3)) << 3) + dlo;
                kb[(base + 0) * 32 + c01] = (unsigned short)u01;
                kb[(base + 1) * 32 + c01] = (unsigned short)(u01 >> 16);
                kb[(base + 2) * 32 + c23] = (unsigned short)u23;
                kb[(base + 3) * 32 + c23] = (unsigned short)(u23 >> 16);
            }
        } else {                 // V transposed [d][row], packed 8B stores
            int col = n0 - 192 + l16; int hh = col >> 5; int d = col & 31;
            #pragma unroll
            for (int mt = 0; mt < 4; ++mt) {
                union { unsigned u[2]; ushort4 s; } pk;
                pk.u[0] = pk2(acc[mt][0], acc[mt][1]);
                pk.u[1] = pk2(acc[mt][2], acc[mt][3]);
                *(ushort4*)&vt[(hh * 32 + d) * VST + mt * 16 + quad * 4] = pk.s;
            }
        }
    }
    __syncthreads();

    // ---- attention, swapped QK^T: lane holds P row q=m0+l16, k=nt*16+quad*4+r ----
    {
        const bool bh = (wh == 15), bw = (ww == 15);
        const bool edge = bh || bw;
        const int qtok = m0 + l16;
        const int qrr = bh ? (((qtok >> 3) < 4) ? 1 : 2) : 0;
        const int qcc = bw ? (((qtok & 7) < 4) ? 1 : 2) : 0;

        for (int h = 0; h < 3; ++h) {
            // K as A-operand, Q as B-operand
            short8 qa = *(const short8*)&xs[(m0 + l16) * XST + h * 32 + quad * 8];
            f32x4 s[4];
            #pragma unroll
            for (int nt = 0; nt < 4; ++nt) {
                int rowk = h * 64 + nt * 16 + l16;
                short8 kf = *(const short8*)&kb[rowk * 32 + ((quad ^ ((rowk >> 1) & 3)) << 3)];
                f32x4 z = (f32x4){0.f, 0.f, 0.f, 0.f};
                s[nt] = __builtin_amdgcn_mfma_f32_16x16x32_bf16(kf, qa, z, 0, 0, 0);
            }
            float p[4][4];
            float rs = 0.f;
            #pragma unroll
            for (int nt = 0; nt < 4; ++nt) {
                float bv[4];
                if (bias2) {
                    int kpb = nt * 8 + quad * 2;              // k-pair base
                    unsigned u0 = bias2[(h * 32 + kpb) * 64 + qtok];
                    unsigned u1 = bias2[(h * 32 + kpb + 1) * 64 + qtok];
                    bv[0] = blo(u0); bv[1] = bhi(u0);
                    bv[2] = blo(u1); bv[3] = bhi(u1);
                } else {
                    #pragma unroll
                    for (int r = 0; r < 4; ++r)
                        bv[r] = rel_bias[(h * 64 + qtok) * 64 + nt * 16 + quad * 4 + r] * INV_LN2;
                }
                #pragma unroll
                for (int r = 0; r < 4; ++r) {
                    int ktok = nt * 16 + quad * 4 + r;
                    float arg = s[nt][r] + bv[r];
                    if (edge) {
                        int krr = bh ? (((ktok >> 3) < 4) ? 1 : 2) : 0;
                        int kcc = bw ? (((ktok & 7) < 4) ? 1 : 2) : 0;
                        if (krr != qrr || kcc != qcc) arg -= MASK_NEG;
                    }
                    float e = exp2f(arg);     // v_exp_f32, scale folded into Q/bias
                    p[nt][r] = e;
                    rs += e;
                }
            }
            rs += __shfl_xor(rs, 16);          // full row-sum across the 4 quads
            rs += __shfl_xor(rs, 32);
            float rinv = 1.0f / rs;

            // normalize + pack: w2[nt][i] = bf16x2(p[nt][2i], p[nt][2i+1])
            unsigned w2[4][2];
            #pragma unroll
            for (int nt = 0; nt < 4; ++nt) {
                w2[nt][0] = pk2(p[nt][0] * rinv, p[nt][1] * rinv);
                w2[nt][1] = pk2(p[nt][2] * rinv, p[nt][3] * rinv);
            }
            // gather C-layout -> A-frag:  pa[kk][j] = P[q=m0+l16][k=kk*32+quad*8+j]
            //   dest word w (j=2w,2w+1): source lane (2*(quad&1)+(w>>1))*16 + l16,
            //   value w2[2kk + (quad>>1)][w&1]
            short8 pa[2];
            #pragma unroll
            for (int kk = 0; kk < 2; ++kk) {
                union { unsigned u[4]; short8 s8; } uw;
                #pragma unroll
                for (int w = 0; w < 4; ++w) {
                    int src = (2 * (quad & 1) + (w >> 1)) * 16 + l16;
                    int lo = __shfl((int)w2[2 * kk][w & 1], src);
                    int hi = __shfl((int)w2[2 * kk + 1][w & 1], src);
                    uw.u[w] = (quad & 2) ? (unsigned)hi : (unsigned)lo;
                }
                pa[kk] = uw.s8;
            }

            f32x4 o0 = (f32x4){0.f, 0.f, 0.f, 0.f};
            f32x4 o1 = o0;
            #pragma unroll
            for (int kk = 0; kk < 2; ++kk) {
                short8 v0 = *(const short8*)&vt[(h * 32 + l16) * VST + kk * 32 + quad * 8];
                short8 v1 = *(const short8*)&vt[(h * 32 + 16 + l16) * VST + kk * 32 + quad * 8];
                o0 = __builtin_amdgcn_mfma_f32_16x16x32_bf16(pa[kk], v0, o0, 0, 0, 0);
                o1 = __builtin_amdgcn_mfma_f32_16x16x32_bf16(pa[kk], v1, o1, 0, 0, 0);
            }
            // attn-out -> xs (rows wave-private; P already normalized)
            int ob = (m0 + quad * 4) * XST + h * 32 + l16;
            unsigned a01 = pk2(o0[0], o0[1]);
            unsigned a23 = pk2(o0[2], o0[3]);
            unsigned b01 = pk2(o1[0], o1[1]);
            unsigned b23 = pk2(o1[2], o1[3]);
            xs[ob]                = (unsigned short)a01;
            xs[ob + XST]          = (unsigned short)(a01 >> 16);
            xs[ob + 2 * XST]      = (unsigned short)a23;
            xs[ob + 3 * XST]      = (unsigned short)(a23 >> 16);
            xs[ob + 16]           = (unsigned short)b01;
            xs[ob + XST + 16]     = (unsigned short)(b01 >> 16);
            xs[ob + 2 * XST + 16] = (unsigned short)b23;
            xs[ob + 3 * XST + 16] = (unsigned short)(b23 >> 16);
        }
    }
    __syncthreads();

    // ---- proj GEMM: 64x96, wave wv does m-tile wv x (6 n-tiles) x (3 k-steps) ----
    {
        short8 pja[3];
        #pragma unroll
        for (int ks = 0; ks < 3; ++ks)
            pja[ks] = *(const short8*)&xs[(m0 + l16) * XST + ks * 32 + quad * 8];

        int rowbase[4];
        #pragma unroll
        for (int r = 0; r < 4; ++r) {
            int tok = m0 + quad * 4 + r;
            int tr = tok >> 3, tc = tok & 7;
            int gh = (wh * 8 + tr + 4) & 127;
            int gw = (ww * 8 + tc + 4) & 127;
            rowbase[r] = ((bb * 128 + gh) * 128 + gw) * 96;
        }
        #pragma unroll
        for (int nt = 0; nt < 6; ++nt) {
            const int n0 = nt * 16;
            float bias = wprjb[n0 + l16];
            f32x4 acc = (f32x4){bias, bias, bias, bias};
            #pragma unroll
            for (int ks = 0; ks < 3; ++ks) {
                short8 bf = *(const short8*)&wproj[(n0 + l16) * 96 + ks * 32 + quad * 8];
                acc = __builtin_amdgcn_mfma_f32_16x16x32_bf16(pja[ks], bf, acc, 0, 0, 0);
            }
            #pragma unroll
            for (int r = 0; r < 4; ++r)
                out[rowbase[r] + n0 + l16] = acc[r];
        }
    }
}

extern "C" void kernel_launch(void* const* d_in, const int* in_sizes, int n_in,
                              void* d_out, int out_size, void* d_ws, size_t ws_size,
                              hipStream_t stream) {
    const float* x        = (const float*)d_in[0];
    const float* qkv_w    = (const float*)d_in[1];
    const float* qkv_b    = (const float*)d_in[2];
    const float* proj_w   = (const float*)d_in[3];
    const float* proj_b   = (const float*)d_in[4];
    const float* rel_bias = (const float*)d_in[5];
    float* out = (float*)d_out;

    const unsigned* bias2 = nullptr;
    if (ws_size >= (size_t)WS_TOTAL_BYTES)
        bias2 = (const unsigned*)((const char*)d_ws + WS_BIAST_BYTES);

    hipLaunchKernelGGL(prep_weights, dim3(170), dim3(256), 0, stream,
                       qkv_w, qkv_b, proj_w, proj_b, rel_bias, d_ws, bias2 ? 1 : 0);
    hipLaunchKernelGGL(swin_mfma, dim3(4096), dim3(256), 0, stream,
                       x, rel_bias, bias2, (const void*)d_ws, out);
}

// Round 4
// 235.125 us; speedup vs baseline: 1.0220x; 1.0220x over previous
//
#include <hip/hip_runtime.h>
#include <hip/hip_bf16.h>

// Swin shifted-window attention, fused, bf16 MFMA (16x16x32).
// B=16 H=W=128 C=96 NH=3 d=32 WS=8 SS=4 -> L=64 tokens/window, 4096 blocks.
// R8 = R7 (verified) + latency-hiding restructure, layouts untouched:
//   - 2-deep head software pipeline: QK(h+1) issued before SOFTPV(h) so the
//     exp/shuffle/PV chain of head h overlaps the MFMA/VMEM of head h+1.
//     Order: QK0 QK1 SOFTPV0 QK2 SOFTPV1 SOFTPV2 (static S arrays sA/sB/sC).
//   - bias (+mask on edge windows) folded into the QK accumulator INIT:
//     acc_in = bias+mask, so bias loads + mask VALU hide under MFMA latency
//     and the dependent post-MFMA adds disappear. Numerically identical.
//   - attn->proj __syncthreads removed: proj reads only rows m0..m0+15 of xs,
//     all written by the same wave (same-wave LDS program order).
// Fragment layouts (verified on gfx950 via R4/R6):
//   A: lane holds A[m=lane&15][k=quad*8+j]
//   B: lane holds B[k=quad*8+j][n=lane&15]
//   C/D: lane holds (row=quad*4+reg, col=lane&15)

typedef __attribute__((ext_vector_type(8))) short short8;
typedef __attribute__((ext_vector_type(4))) float f32x4;

#define XST 104   // xs row stride (bf16): 208B, 2-way banks (free)
#define VST 72    // vt row stride: 144B

// ws layout:
//   shorts [0        .. 27647]  qkv_w bf16, row-major [col][96], cols 0..95 pre-scaled by qs/ln2
//   shorts [27648    .. 36863]  proj_w bf16, row-major [col][96]
//   bytes  73728..74879         qkv_b fp32 (288), cols 0..95 pre-scaled by qs/ln2
//   bytes  74880..75263         proj_b fp32 (96)
//   bytes  75776..100351        bias2 u32 [3][32][64]: bf16x2(rel_bias[h][q][2kp], [2kp+1]) / ln2
#define WS_QKVW 0
#define WS_PROJW 27648
#define WS_QKVB_BYTES 73728
#define WS_PROJB_BYTES 74880
#define WS_BIAST_BYTES 75776
#define WS_TOTAL_BYTES (WS_BIAST_BYTES + 3 * 32 * 64 * 4)

#define INV_LN2 1.4426950408889634f
#define MASK_NEG 144.26950408889634f   // 100/ln2

__device__ __forceinline__ unsigned short f2b(float f) {
    union { float f; unsigned u; } v; v.f = f;
    unsigned r = v.u + 0x7fffu + ((v.u >> 16) & 1u);   // RNE
    return (unsigned short)(r >> 16);
}

// packed f32x2 -> bf16x2 (RNE): lo = a, hi = b
__device__ __forceinline__ unsigned pk2(float a, float b) {
    union { __hip_bfloat162 h; unsigned u; } z;
    z.h = __float22bfloat162_rn(make_float2(a, b));
    return z.u;
}
__device__ __forceinline__ float blo(unsigned u) {
    union { unsigned u; float f; } z; z.u = u << 16; return z.f;
}
__device__ __forceinline__ float bhi(unsigned u) {
    union { unsigned u; float f; } z; z.u = u & 0xffff0000u; return z.f;
}

__global__ void prep_weights(const float* __restrict__ qkv_w,
                             const float* __restrict__ qkv_b,
                             const float* __restrict__ proj_w,
                             const float* __restrict__ proj_b,
                             const float* __restrict__ rel_bias,
                             void* __restrict__ ws, int do_bias)
{
    unsigned short* wsh = (unsigned short*)ws;
    float* fqb = (float*)((char*)ws + WS_QKVB_BYTES);
    float* fpb = (float*)((char*)ws + WS_PROJB_BYTES);
    unsigned* fb2 = (unsigned*)((char*)ws + WS_BIAST_BYTES);
    const float qs = 0.17677669529663687f * INV_LN2;  // 1/sqrt(32)/ln2

    int idx = blockIdx.x * 256 + threadIdx.x;
    if (idx < 27648) {                       // qkv_w
        int col = idx / 96;
        float v = qkv_w[idx];
        if (col < 96) v *= qs;
        wsh[WS_QKVW + idx] = f2b(v);
    } else if (idx < 36864) {                // proj_w
        wsh[WS_PROJW + (idx - 27648)] = f2b(proj_w[idx - 27648]);
    } else if (idx < 37152) {                // qkv_b
        int col = idx - 36864;
        float v = qkv_b[col];
        if (col < 96) v *= qs;
        fqb[col] = v;
    } else if (idx < 37248) {                // proj_b
        fpb[idx - 37152] = proj_b[idx - 37152];
    } else if (do_bias && idx < 43392) {     // bias2[h][kp][q]
        int i2 = idx - 37248;                // [0, 6144)
        int h = i2 >> 11;                    // 2048 per head
        int rem = i2 & 2047;
        int kp = rem >> 6, q = rem & 63;
        float lo = rel_bias[(h * 64 + q) * 64 + 2 * kp]     * INV_LN2;
        float hi = rel_bias[(h * 64 + q) * 64 + 2 * kp + 1] * INV_LN2;
        fb2[i2] = pk2(lo, hi);
    }
}

__global__ __launch_bounds__(256, 4) void swin_mfma(
    const float* __restrict__ x,
    const float* __restrict__ rel_bias,     // [h][q][k] fallback path
    const unsigned* __restrict__ bias2,     // [h][kp][q] bf16x2/ln2 in ws, or nullptr
    const void* __restrict__ ws,
    float* __restrict__ out)
{
    const unsigned short* wqkv  = (const unsigned short*)ws + WS_QKVW;
    const unsigned short* wproj = (const unsigned short*)ws + WS_PROJW;
    const float* wqkvb = (const float*)((const char*)ws + WS_QKVB_BYTES);
    const float* wprjb = (const float*)((const char*)ws + WS_PROJB_BYTES);

    __shared__ __align__(16) unsigned short xs[64 * XST];      // 13.0 KB: x -> Q -> attn-out
    __shared__ __align__(16) unsigned short kb[3 * 64 * 32];   // 12.0 KB: K, chunk-XOR swizzled
    __shared__ __align__(16) unsigned short vt[3 * 32 * VST];  // 13.5 KB: v transposed [d][row]
    // total 39424 B -> 4 blocks/CU

    const int t    = threadIdx.x;
    const int wv   = t >> 6;          // wave id 0..3 = q-strip owner
    const int lane = t & 63;
    const int quad = lane >> 4;
    const int l16  = lane & 15;
    const int m0   = wv * 16;

    const int blk = blockIdx.x;
    const int bb  = blk >> 8;
    const int win = blk & 255;
    const int wh  = win >> 4, ww = win & 15;

    // ---- stage x window -> bf16 LDS (rolled coords) ----
    for (int idx = t; idx < 1536; idx += 256) {
        int row = idx / 24;
        int c4  = idx - row * 24;
        int r = row >> 3, c = row & 7;
        int gh = (wh * 8 + r + 4) & 127;
        int gw = (ww * 8 + c + 4) & 127;
        float4 v = *(const float4*)&x[(((bb * 128 + gh) * 128 + gw) * 96) + c4 * 4];
        union { unsigned u[2]; ushort4 s; } pk;
        pk.u[0] = pk2(v.x, v.y);
        pk.u[1] = pk2(v.z, v.w);
        *(ushort4*)&xs[row * XST + c4 * 4] = pk.s;
    }
    __syncthreads();

    // ---- preload X A-frags; then xs is dead and can hold Q ----
    short8 af[4][3];
    #pragma unroll
    for (int mt = 0; mt < 4; ++mt)
        #pragma unroll
        for (int ks = 0; ks < 3; ++ks)
            af[mt][ks] = *(const short8*)&xs[(mt * 16 + l16) * XST + ks * 32 + quad * 8];
    __syncthreads();   // all waves done reading x from xs

    // ---- QKV GEMM: 64x288 = (4 m-tiles) x (18 n-tiles) x (3 k-steps) ----
    for (int nt = wv; nt < 18; nt += 4) {
        const int n0 = nt * 16;
        float bias = wqkvb[n0 + l16];
        f32x4 acc[4];
        #pragma unroll
        for (int mt = 0; mt < 4; ++mt) acc[mt] = (f32x4){bias, bias, bias, bias};
        #pragma unroll
        for (int ks = 0; ks < 3; ++ks) {
            short8 bf = *(const short8*)&wqkv[(n0 + l16) * 96 + ks * 32 + quad * 8];
            #pragma unroll
            for (int mt = 0; mt < 4; ++mt)
                acc[mt] = __builtin_amdgcn_mfma_f32_16x16x32_bf16(af[mt][ks], bf, acc[mt], 0, 0, 0);
        }
        if (nt < 6) {            // Q (pre-scaled by qs/ln2) -> xs[row][col]
            int col = n0 + l16;
            #pragma unroll
            for (int mt = 0; mt < 4; ++mt) {
                unsigned u01 = pk2(acc[mt][0], acc[mt][1]);
                unsigned u23 = pk2(acc[mt][2], acc[mt][3]);
                int rb = (mt * 16 + quad * 4) * XST + col;
                xs[rb]           = (unsigned short)u01;
                xs[rb + XST]     = (unsigned short)(u01 >> 16);
                xs[rb + 2 * XST] = (unsigned short)u23;
                xs[rb + 3 * XST] = (unsigned short)(u23 >> 16);
            }
        } else if (nt < 12) {    // K row-major, stride 32, 16B-chunk XOR swizzle
            int col = n0 - 96 + l16; int hh = col >> 5; int d = col & 31;
            int dch = d >> 3, dlo = d & 7;
            #pragma unroll
            for (int mt = 0; mt < 4; ++mt) {
                int base = hh * 64 + mt * 16 + quad * 4;      // even
                unsigned u01 = pk2(acc[mt][0], acc[mt][1]);
                unsigned u23 = pk2(acc[mt][2], acc[mt][3]);
                int c01 = ((dch ^ ((base >> 1) & 3)) << 3) + dlo;
                int c23 = ((dch ^ (((base >> 1) + 1) & 3)) << 3) + dlo;
                kb[(base + 0) * 32 + c01] = (unsigned short)u01;
                kb[(base + 1) * 32 + c01] = (unsigned short)(u01 >> 16);
                kb[(base + 2) * 32 + c23] = (unsigned short)u23;
                kb[(base + 3) * 32 + c23] = (unsigned short)(u23 >> 16);
            }
        } else {                 // V transposed [d][row], packed 8B stores
            int col = n0 - 192 + l16; int hh = col >> 5; int d = col & 31;
            #pragma unroll
            for (int mt = 0; mt < 4; ++mt) {
                union { unsigned u[2]; ushort4 s; } pk;
                pk.u[0] = pk2(acc[mt][0], acc[mt][1]);
                pk.u[1] = pk2(acc[mt][2], acc[mt][3]);
                *(ushort4*)&vt[(hh * 32 + d) * VST + mt * 16 + quad * 4] = pk.s;
            }
        }
    }
    __syncthreads();

    // ---- attention, swapped QK^T, 2-deep head pipeline ----
    // lane holds P row q=m0+l16, k=nt*16+quad*4+r
    {
        const bool bh = (wh == 15), bw = (ww == 15);
        const bool edge = bh || bw;
        const int qtok = m0 + l16;
        const int qrr = bh ? (((qtok >> 3) < 4) ? 1 : 2) : 0;
        const int qcc = bw ? (((qtok & 7) < 4) ? 1 : 2) : 0;

        // QK for head h: bias(+mask) folded into the accumulator init.
        auto qkhead = [&](f32x4* s, int h) {
            short8 qa = *(const short8*)&xs[(m0 + l16) * XST + h * 32 + quad * 8];
            #pragma unroll
            for (int nt = 0; nt < 4; ++nt) {
                float bv[4];
                if (bias2) {
                    int kpb = nt * 8 + quad * 2;              // k-pair base
                    unsigned u0 = bias2[(h * 32 + kpb) * 64 + qtok];
                    unsigned u1 = bias2[(h * 32 + kpb + 1) * 64 + qtok];
                    bv[0] = blo(u0); bv[1] = bhi(u0);
                    bv[2] = blo(u1); bv[3] = bhi(u1);
                } else {
                    #pragma unroll
                    for (int r = 0; r < 4; ++r)
                        bv[r] = rel_bias[(h * 64 + qtok) * 64 + nt * 16 + quad * 4 + r] * INV_LN2;
                }
                f32x4 z;
                if (edge) {
                    #pragma unroll
                    for (int r = 0; r < 4; ++r) {
                        int ktok = nt * 16 + quad * 4 + r;
                        int krr = bh ? (((ktok >> 3) < 4) ? 1 : 2) : 0;
                        int kcc = bw ? (((ktok & 7) < 4) ? 1 : 2) : 0;
                        z[r] = bv[r] - ((krr != qrr || kcc != qcc) ? MASK_NEG : 0.f);
                    }
                } else {
                    z[0] = bv[0]; z[1] = bv[1]; z[2] = bv[2]; z[3] = bv[3];
                }
                int rowk = h * 64 + nt * 16 + l16;
                short8 kf = *(const short8*)&kb[rowk * 32 + ((quad ^ ((rowk >> 1) & 3)) << 3)];
                s[nt] = __builtin_amdgcn_mfma_f32_16x16x32_bf16(kf, qa, z, 0, 0, 0);
            }
        };

        // softmax + gather + PV + O-store for head h (consumes s).
        auto softpv = [&](f32x4* s, int h) {
            float p[4][4];
            float rs = 0.f;
            #pragma unroll
            for (int nt = 0; nt < 4; ++nt) {
                #pragma unroll
                for (int r = 0; r < 4; ++r) {
                    float e = exp2f(s[nt][r]);   // bias+mask already in s
                    p[nt][r] = e;
                    rs += e;
                }
            }
            rs += __shfl_xor(rs, 16);            // full row-sum across the 4 quads
            rs += __shfl_xor(rs, 32);
            float rinv = 1.0f / rs;

            unsigned w2[4][2];
            #pragma unroll
            for (int nt = 0; nt < 4; ++nt) {
                w2[nt][0] = pk2(p[nt][0] * rinv, p[nt][1] * rinv);
                w2[nt][1] = pk2(p[nt][2] * rinv, p[nt][3] * rinv);
            }
            // gather C-layout -> A-frag:  pa[kk][j] = P[q=m0+l16][k=kk*32+quad*8+j]
            short8 pa[2];
            #pragma unroll
            for (int kk = 0; kk < 2; ++kk) {
                union { unsigned u[4]; short8 s8; } uw;
                #pragma unroll
                for (int w = 0; w < 4; ++w) {
                    int src = (2 * (quad & 1) + (w >> 1)) * 16 + l16;
                    int lo = __shfl((int)w2[2 * kk][w & 1], src);
                    int hi = __shfl((int)w2[2 * kk + 1][w & 1], src);
                    uw.u[w] = (quad & 2) ? (unsigned)hi : (unsigned)lo;
                }
                pa[kk] = uw.s8;
            }

            f32x4 o0 = (f32x4){0.f, 0.f, 0.f, 0.f};
            f32x4 o1 = o0;
            #pragma unroll
            for (int kk = 0; kk < 2; ++kk) {
                short8 v0 = *(const short8*)&vt[(h * 32 + l16) * VST + kk * 32 + quad * 8];
                short8 v1 = *(const short8*)&vt[(h * 32 + 16 + l16) * VST + kk * 32 + quad * 8];
                o0 = __builtin_amdgcn_mfma_f32_16x16x32_bf16(pa[kk], v0, o0, 0, 0, 0);
                o1 = __builtin_amdgcn_mfma_f32_16x16x32_bf16(pa[kk], v1, o1, 0, 0, 0);
            }
            // attn-out -> xs (rows wave-private; P already normalized)
            int ob = (m0 + quad * 4) * XST + h * 32 + l16;
            unsigned a01 = pk2(o0[0], o0[1]);
            unsigned a23 = pk2(o0[2], o0[3]);
            unsigned b01 = pk2(o1[0], o1[1]);
            unsigned b23 = pk2(o1[2], o1[3]);
            xs[ob]                = (unsigned short)a01;
            xs[ob + XST]          = (unsigned short)(a01 >> 16);
            xs[ob + 2 * XST]      = (unsigned short)a23;
            xs[ob + 3 * XST]      = (unsigned short)(a23 >> 16);
            xs[ob + 16]           = (unsigned short)b01;
            xs[ob + XST + 16]     = (unsigned short)(b01 >> 16);
            xs[ob + 2 * XST + 16] = (unsigned short)b23;
            xs[ob + 3 * XST + 16] = (unsigned short)(b23 >> 16);
        };

        // 2-deep pipeline: QK(h+1) in flight while SOFTPV(h) runs.
        f32x4 sA[4], sB[4], sC[4];
        qkhead(sA, 0);
        qkhead(sB, 1);
        softpv(sA, 0);
        qkhead(sC, 2);
        softpv(sB, 1);
        softpv(sC, 2);
    }
    // NO __syncthreads: proj reads only this wave's rows m0..m0+15 of xs,
    // written by this same wave (same-wave LDS program order).

    // ---- proj GEMM: 64x96, wave wv does m-tile wv x (6 n-tiles) x (3 k-steps) ----
    {
        short8 pja[3];
        #pragma unroll
        for (int ks = 0; ks < 3; ++ks)
            pja[ks] = *(const short8*)&xs[(m0 + l16) * XST + ks * 32 + quad * 8];

        int rowbase[4];
        #pragma unroll
        for (int r = 0; r < 4; ++r) {
            int tok = m0 + quad * 4 + r;
            int tr = tok >> 3, tc = tok & 7;
            int gh = (wh * 8 + tr + 4) & 127;
            int gw = (ww * 8 + tc + 4) & 127;
            rowbase[r] = ((bb * 128 + gh) * 128 + gw) * 96;
        }
        #pragma unroll
        for (int nt = 0; nt < 6; ++nt) {
            const int n0 = nt * 16;
            float bias = wprjb[n0 + l16];
            f32x4 acc = (f32x4){bias, bias, bias, bias};
            #pragma unroll
            for (int ks = 0; ks < 3; ++ks) {
                short8 bf = *(const short8*)&wproj[(n0 + l16) * 96 + ks * 32 + quad * 8];
                acc = __builtin_amdgcn_mfma_f32_16x16x32_bf16(pja[ks], bf, acc, 0, 0, 0);
            }
            #pragma unroll
            for (int r = 0; r < 4; ++r)
                out[rowbase[r] + n0 + l16] = acc[r];
        }
    }
}

extern "C" void kernel_launch(void* const* d_in, const int* in_sizes, int n_in,
                              void* d_out, int out_size, void* d_ws, size_t ws_size,
                              hipStream_t stream) {
    const float* x        = (const float*)d_in[0];
    const float* qkv_w    = (const float*)d_in[1];
    const float* qkv_b    = (const float*)d_in[2];
    const float* proj_w   = (const float*)d_in[3];
    const float* proj_b   = (const float*)d_in[4];
    const float* rel_bias = (const float*)d_in[5];
    float* out = (float*)d_out;

    const unsigned* bias2 = nullptr;
    if (ws_size >= (size_t)WS_TOTAL_BYTES)
        bias2 = (const unsigned*)((const char*)d_ws + WS_BIAST_BYTES);

    hipLaunchKernelGGL(prep_weights, dim3(170), dim3(256), 0, stream,
                       qkv_w, qkv_b, proj_w, proj_b, rel_bias, d_ws, bias2 ? 1 : 0);
    hipLaunchKernelGGL(swin_mfma, dim3(4096), dim3(256), 0, stream,
                       x, rel_bias, bias2, (const void*)d_ws, out);
}